// Round 7
// baseline (202.499 us; speedup 1.0000x reference)
//
#include <hip/hip_runtime.h>
#include <stdint.h>

// FactorLayer: B=4096, D=4096, T=16, float32.
// X = znorm(inputs); Y = X@W_static; Z = X@W. All deflations use ORIGINAL X,
// so conv_j is fixed once born; everything lives in span{Y0..Y15, 1}.
// Sequential scan collapses to 17-dim recurrences on the Gram of [Y|Z|1];
// Out = Z - [Y|1] @ Wmat (17x16).  4 plain launches.
// R3: cooperative launch silently no-ops in this harness.
// R5 (166us): kB 41us, VALUBusy 18%, Occupancy 17% -- GRID-limited (512 blocks
//   = 2 blocks/CU). R6 prefetch was neutral: not a pipelining problem.
// R7: kB -> 1024 blocks (32 rg x 128 rows, 4 blocks/CU, 16 waves/CU); waves
//   0-1 compute j<16, waves 2-3 j>=16 (h wave-uniform -> weights stay s_load).

#define BB 4096
#define DD 4096
#define EPSF 1e-6f

// ws layout (float indices), ~22 MB total
#define O_PART    0u          // [128 rowgroups][8192]: colsum(0..4095), colsq(4096..8191)
#define O_WSF     1048576u    // [d][32]: j<16 -> W_static (Y), j>=16 -> W (Z)
#define O_GRAMM   1179648u    // 8 copies x 1120 (33x33, upper-tri used)
#define O_YZ      1188608u    // [4096][32]  (byte offset 16B-aligned)
#define O_YPART   1319680u    // [32 dgroups][4096][32]

__device__ __forceinline__ int gidx(int a, int b) {   // upper-tri gram index
    int lo = a < b ? a : b, hi = a < b ? b : a;
    return lo * 33 + hi;
}

// ============ kA: stats partials + zero gram + stage weights ================
__global__ __launch_bounds__(256, 2)
void kA(const float* __restrict__ in, const float* __restrict__ W,
        const float* __restrict__ Wstat, float* __restrict__ ws) {
    int b = blockIdx.x, t = threadIdx.x;
    int idx = b * 256 + t;
    if (idx < 8960) ws[O_GRAMM + idx] = 0.f;          // 8 gram copies
    {                                                  // weights: 1 elt/thread
        int d = idx >> 5, j = idx & 31;
        ws[O_WSF + idx] = (j < 16) ? Wstat[d * 16 + j] : W[d * 16 + (j - 16)];
    }
    // stats: 4 colgroups x 128 rowgroups(32 rows); thread owns 4 cols
    int cgk = b & 3, rg = b >> 2;
    int c0 = cgk * 1024 + t * 4, r0 = rg * 32;
    float s0=0.f,s1=0.f,s2=0.f,s3=0.f,q0=0.f,q1=0.f,q2=0.f,q3=0.f;
    #pragma unroll 4
    for (int r = 0; r < 32; ++r) {
        float4 u = *(const float4*)&in[(size_t)(r0 + r) * DD + c0];
        s0 += u.x; q0 += u.x*u.x;  s1 += u.y; q1 += u.y*u.y;
        s2 += u.z; q2 += u.z*u.z;  s3 += u.w; q3 += u.w*u.w;
    }
    float* part = ws + O_PART + (size_t)rg * 8192;
    *(float4*)&part[c0]        = make_float4(s0, s1, s2, s3);
    *(float4*)&part[4096 + c0] = make_float4(q0, q1, q2, q3);
}

// ============ kB: finalize mu/inv; pipelined normalized GEMM ================
// 1024 blocks = 32 dgroups(128 d) x 32 rowgroups(128 rows). 4 blocks/CU.
// Thread role: row = t&127, h = t>>7 (wave-uniform j-half).
__global__ __launch_bounds__(256, 4)
void kB(const float* __restrict__ in, const float* __restrict__ ws,
        float* __restrict__ ypart) {
    __shared__ __align__(16) float tile[128 * 33];    // 16.9 KB
    __shared__ __align__(16) float mu_s[128];
    __shared__ __align__(16) float inv_s[128];
    __shared__ __align__(16) float muinv_s[128];
    int b = blockIdx.x, t = threadIdx.x;
    int dg = b & 31, rg = b >> 5;
    int dbase = dg * 128, rowbase = rg * 128;
    {   // prologue: reduce partials for this block's 128 cols (L2/L3-hot)
        int half = t >> 7, ci = t & 127;
        const float* p0 = ws + O_PART + (size_t)half * 4096 + dbase + ci;
        float a = 0.f;
        #pragma unroll 8
        for (int g = 0; g < 128; ++g) a += p0[(size_t)g * 8192];
        if (half == 0) mu_s[ci] = a * (1.0f / BB);
        __syncthreads();
        if (half == 1) {
            float m = mu_s[ci];
            float var = a * (1.0f / BB) - m * m; if (var < 0.f) var = 0.f;
            float iv = 1.0f / (sqrtf(var) + EPSF);
            inv_s[ci] = iv; muinv_s[ci] = m * iv;
        }
        __syncthreads();
    }
    float acc[16];
    #pragma unroll
    for (int i = 0; i < 16; ++i) acc[i] = 0.f;
    int c = t & 7, rr = t >> 3;                       // staging: chunk, row (rr<32)
    int row = t & 127, h = t >> 7;                    // compute: row, j-half
    const float* wsf = ws + O_WSF;
    const float* inrow = in + (size_t)rowbase * DD + dbase + c * 4;
    float4 pf[4];                                     // register prefetch buffer
    #pragma unroll
    for (int s = 0; s < 4; ++s)                       // preload stage 0
        pf[s] = *(const float4*)&inrow[(size_t)(s * 32 + rr) * DD];
    for (int stage = 0; stage < 4; ++stage) {
        int ds0 = stage * 32;                         // local d-offset
        float4 iv4 = *(const float4*)&inv_s[ds0 + c * 4];
        float4 mi4 = *(const float4*)&muinv_s[ds0 + c * 4];
        #pragma unroll
        for (int s = 0; s < 4; ++s) {                 // regs -> LDS, normalized
            int base = (s * 32 + rr) * 33 + c * 4;
            tile[base + 0] = pf[s].x * iv4.x - mi4.x;
            tile[base + 1] = pf[s].y * iv4.y - mi4.y;
            tile[base + 2] = pf[s].z * iv4.z - mi4.z;
            tile[base + 3] = pf[s].w * iv4.w - mi4.w;
        }
        __syncthreads();
        if (stage < 3) {                              // issue next stage's loads
            #pragma unroll
            for (int s = 0; s < 4; ++s)
                pf[s] = *(const float4*)&inrow[(size_t)(s * 32 + rr) * DD + (stage + 1) * 32];
        }
        const float* trow = tile + row * 33;          // compute current stage
        #pragma unroll 4
        for (int dl = 0; dl < 32; ++dl) {
            float xs = trow[dl];
            const float* wr = wsf + (size_t)(dbase + ds0 + dl) * 32 + h * 16;  // uniform -> s_load
            #pragma unroll
            for (int j = 0; j < 16; ++j) acc[j] += xs * wr[j];
        }
        __syncthreads();
    }
    float* dst = ypart + ((size_t)dg * BB + rowbase + row) * 32 + h * 16;
    #pragma unroll
    for (int j = 0; j < 16; j += 4)
        *(float4*)(dst + j) = make_float4(acc[j], acc[j+1], acc[j+2], acc[j+3]);
}

// ============ kC: reduce ypart -> yz; gram atomics (8-way split) ============
__global__ __launch_bounds__(256, 2)
void kC(float* __restrict__ ws) {
    __shared__ float yz_s[8 * 34];
    int b = blockIdx.x, t = threadIdx.x;
    int rowbase = b * 8;                              // 512 blocks x 8 rows
    int r = t >> 5, c = t & 31;
    const float* yp = ws + O_YPART;
    size_t off = (size_t)(rowbase + r) * 32 + c;
    float s = 0.f;
    #pragma unroll
    for (int dg = 0; dg < 32; ++dg) s += yp[(size_t)dg * (BB * 32) + off];
    ws[O_YZ + off] = s;
    yz_s[r * 34 + c] = s;
    if (c == 0) yz_s[r * 34 + 32] = 1.0f;
    __syncthreads();
    float* gm = ws + O_GRAMM + (size_t)(b & 7) * 1120;
    for (int p = t; p < 561; p += 256) {              // upper-tri pairs i<=j<=32
        int i = 0, rem = p;
        while (rem >= 33 - i) { rem -= 33 - i; ++i; }
        int j = i + rem;
        float a2 = 0.f;
        #pragma unroll
        for (int r2 = 0; r2 < 8; ++r2) a2 += yz_s[r2 * 34 + i] * yz_s[r2 * 34 + j];
        atomicAdd(&gm[i * 33 + j], a2);
    }
}

// ============ kE: barriered 17-dim solve (redundant/block) + epilogue =======
// Basis p=0..15 -> Y[:,p], p=16 -> ones. Gram cols: Y->p, Z_t->16+t, 1->32.
__global__ __launch_bounds__(256, 2)
void kE(const float* __restrict__ ws, float* __restrict__ out) {
    __shared__ __align__(16) float yzs[64 * 36];      // 64 rows of [Y|Z]
    __shared__ float GA[17 * 17], gz[17 * 16], v[15][17], gad[15][16],
                     gzd[15][16], gu[17], u[17], st[2], wm[17 * 16];
    int b = blockIdx.x, t = threadIdx.x;
    int rowbase = b * 64;                             // 64 blocks x 64 rows
    // stage this block's 64 rows of [Y|Z] (512 float4, 2/thread)
    const float4* src = (const float4*)(ws + O_YZ) + (size_t)rowbase * 8;
    #pragma unroll
    for (int k = 0; k < 2; ++k) {
        int idx = k * 256 + t;
        float4 f = src[idx];
        int row = idx >> 3, c4 = (idx & 7) * 4;
        yzs[row * 36 + c4 + 0] = f.x; yzs[row * 36 + c4 + 1] = f.y;
        yzs[row * 36 + c4 + 2] = f.z; yzs[row * 36 + c4 + 3] = f.w;
    }
    // gram (sum of 8 copies) -> LDS, all threads
    const float* gm = ws + O_GRAMM;
    for (int idx = t; idx < 17 * 17; idx += 256) {
        int p = idx / 17, q = idx % 17;
        int gi = gidx(p < 16 ? p : 32, q < 16 ? q : 32);
        float s = 0.f;
        #pragma unroll
        for (int m = 0; m < 8; ++m) s += gm[m * 1120 + gi];
        GA[idx] = s;
    }
    for (int idx = t; idx < 17 * 16; idx += 256) {
        int p = idx / 16, tt = idx % 16;
        int gi = gidx(p < 16 ? p : 32, 16 + tt);
        float s = 0.f;
        #pragma unroll
        for (int m = 0; m < 8; ++m) s += gm[m * 1120 + gi];
        gz[idx] = s;
    }
    if (t < 17) u[t] = (t == 0) ? 1.f : 0.f;
    __syncthreads();
    const float invB = 1.0f / BB;
    for (int i = 0; i < 15; ++i) {
        if (t < 17) {                                 // gu = GA @ u
            float s = 0.f;
            for (int q = 0; q < 17; ++q) s += GA[t * 17 + q] * u[q];
            gu[t] = s;
        }
        __syncthreads();
        if (t == 0) {                                 // stats of c_i
            float mean = gu[16] * invB, e2 = 0.f;
            for (int p = 0; p < 17; ++p) e2 += u[p] * gu[p];
            e2 *= invB;
            float var = e2 - mean * mean; if (var < 0.f) var = 0.f;
            st[0] = mean; st[1] = 1.0f / (sqrtf(var) + EPSF);
        }
        __syncthreads();
        if (t < 17) v[i][t] = (u[t] - (t == 16 ? st[0] : 0.f)) * st[1];
        __syncthreads();
        if (t < 16) {                                 // conv_i . Y[:,k]
            float s = 0.f;
            for (int p = 0; p < 17; ++p) s += v[i][p] * GA[p * 17 + t];
            gad[i][t] = s;
        } else if (t < 32) {                          // conv_i . Z[:,tt]
            int tt = t - 16;
            float s = 0.f;
            for (int p = 0; p < 17; ++p) s += v[i][p] * gz[p * 16 + tt];
            gzd[i][tt] = s;
        }
        __syncthreads();
        if (t < 17) {                                 // u_{i+1}
            float a2 = 0.f;
            for (int j = 0; j <= i; ++j) a2 += v[j][t] * gad[j][i + 1];
            u[t] = ((t == i + 1) ? 1.f : 0.f) - a2 * invB;
        }
        __syncthreads();
    }
    for (int idx = t; idx < 17 * 16; idx += 256) {
        int p = idx / 16, tt = idx % 16;
        float s = 0.f;
        for (int j = 0; j < tt; ++j) s += v[j][p] * gzd[j][tt];
        wm[idx] = s * invB;
    }
    __syncthreads();
    // epilogue: 4 outputs/thread, coalesced float4 store
    int row = t >> 2, c0 = (t & 3) * 4;
    const float* yr = yzs + row * 36;
    float o[4];
    #pragma unroll
    for (int k = 0; k < 4; ++k) o[k] = yr[16 + c0 + k] - wm[16 * 16 + c0 + k];
    #pragma unroll
    for (int p = 0; p < 16; ++p) {
        float yp = yr[p];
        #pragma unroll
        for (int k = 0; k < 4; ++k) o[k] -= yp * wm[p * 16 + c0 + k];
    }
    *(float4*)&out[(size_t)rowbase * 16 + t * 4] = make_float4(o[0], o[1], o[2], o[3]);
}

extern "C" void kernel_launch(void* const* d_in, const int* in_sizes, int n_in,
                              void* d_out, int out_size, void* d_ws, size_t ws_size,
                              hipStream_t stream) {
    const float* in    = (const float*)d_in[0];
    const float* W     = (const float*)d_in[1];
    const float* Wstat = (const float*)d_in[2];
    float* ws  = (float*)d_ws;
    float* out = (float*)d_out;

    kA<<<dim3(512),  dim3(256), 0, stream>>>(in, W, Wstat, ws);
    kB<<<dim3(1024), dim3(256), 0, stream>>>(in, ws, ws + O_YPART);
    kC<<<dim3(512),  dim3(256), 0, stream>>>(ws);
    kE<<<dim3(64),   dim3(256), 0, stream>>>(ws, out);
}

// Round 8
// 156.398 us; speedup vs baseline: 1.2948x; 1.2948x over previous
//
#include <hip/hip_runtime.h>
#include <stdint.h>

// FactorLayer: B=4096, D=4096, T=16, float32.
// X = znorm(inputs); Y = X@W_static; Z = X@W. All deflations use ORIGINAL X,
// so conv_j is fixed once born; everything lives in span{Y0..Y15, 1}.
// Sequential scan collapses to 17-dim recurrences on the Gram of [Y|Z|1];
// Out = Z - [Y|1] @ Wmat (17x16).  4 plain launches.
// R3: cooperative launch silently no-ops in this harness.
// R5 (166us): kB 41us grid-limited (512 blocks = 2/CU, Occ 17%).
// R7 (202us): kB 1024 blocks BUT weight ptr depended on h=t>>7 -> compiler
//   couldn't prove uniform -> SGPR 112->32, s_load lost, VMEM chain, 79us.
// R8: h = readfirstlane(t>>7) (truly wave-uniform: wave w -> t>>7 == w>>1)
//   restores s_load weights AND keeps 4 blocks/CU. Only that line changed.

#define BB 4096
#define DD 4096
#define EPSF 1e-6f

// ws layout (float indices), ~22 MB total
#define O_PART    0u          // [128 rowgroups][8192]: colsum(0..4095), colsq(4096..8191)
#define O_WSF     1048576u    // [d][32]: j<16 -> W_static (Y), j>=16 -> W (Z)
#define O_GRAMM   1179648u    // 8 copies x 1120 (33x33, upper-tri used)
#define O_YZ      1188608u    // [4096][32]  (byte offset 16B-aligned)
#define O_YPART   1319680u    // [32 dgroups][4096][32]

__device__ __forceinline__ int gidx(int a, int b) {   // upper-tri gram index
    int lo = a < b ? a : b, hi = a < b ? b : a;
    return lo * 33 + hi;
}

// ============ kA: stats partials + zero gram + stage weights ================
__global__ __launch_bounds__(256, 2)
void kA(const float* __restrict__ in, const float* __restrict__ W,
        const float* __restrict__ Wstat, float* __restrict__ ws) {
    int b = blockIdx.x, t = threadIdx.x;
    int idx = b * 256 + t;
    if (idx < 8960) ws[O_GRAMM + idx] = 0.f;          // 8 gram copies
    {                                                  // weights: 1 elt/thread
        int d = idx >> 5, j = idx & 31;
        ws[O_WSF + idx] = (j < 16) ? Wstat[d * 16 + j] : W[d * 16 + (j - 16)];
    }
    // stats: 4 colgroups x 128 rowgroups(32 rows); thread owns 4 cols
    int cgk = b & 3, rg = b >> 2;
    int c0 = cgk * 1024 + t * 4, r0 = rg * 32;
    float s0=0.f,s1=0.f,s2=0.f,s3=0.f,q0=0.f,q1=0.f,q2=0.f,q3=0.f;
    #pragma unroll 4
    for (int r = 0; r < 32; ++r) {
        float4 u = *(const float4*)&in[(size_t)(r0 + r) * DD + c0];
        s0 += u.x; q0 += u.x*u.x;  s1 += u.y; q1 += u.y*u.y;
        s2 += u.z; q2 += u.z*u.z;  s3 += u.w; q3 += u.w*u.w;
    }
    float* part = ws + O_PART + (size_t)rg * 8192;
    *(float4*)&part[c0]        = make_float4(s0, s1, s2, s3);
    *(float4*)&part[4096 + c0] = make_float4(q0, q1, q2, q3);
}

// ============ kB: finalize mu/inv; pipelined normalized GEMM ================
// 1024 blocks = 32 dgroups(128 d) x 32 rowgroups(128 rows). 4 blocks/CU.
// Thread role: row = t&127, h = readfirstlane(t>>7) (wave-uniform j-half).
__global__ __launch_bounds__(256, 4)
void kB(const float* __restrict__ in, const float* __restrict__ ws,
        float* __restrict__ ypart) {
    __shared__ __align__(16) float tile[128 * 33];    // 16.9 KB
    __shared__ __align__(16) float mu_s[128];
    __shared__ __align__(16) float inv_s[128];
    __shared__ __align__(16) float muinv_s[128];
    int b = blockIdx.x, t = threadIdx.x;
    int dg = b & 31, rg = b >> 5;
    int dbase = dg * 128, rowbase = rg * 128;
    {   // prologue: reduce partials for this block's 128 cols (L2/L3-hot)
        int half = t >> 7, ci = t & 127;
        const float* p0 = ws + O_PART + (size_t)half * 4096 + dbase + ci;
        float a = 0.f;
        #pragma unroll 8
        for (int g = 0; g < 128; ++g) a += p0[(size_t)g * 8192];
        if (half == 0) mu_s[ci] = a * (1.0f / BB);
        __syncthreads();
        if (half == 1) {
            float m = mu_s[ci];
            float var = a * (1.0f / BB) - m * m; if (var < 0.f) var = 0.f;
            float iv = 1.0f / (sqrtf(var) + EPSF);
            inv_s[ci] = iv; muinv_s[ci] = m * iv;
        }
        __syncthreads();
    }
    float acc[16];
    #pragma unroll
    for (int i = 0; i < 16; ++i) acc[i] = 0.f;
    int c = t & 7, rr = t >> 3;                       // staging: chunk, row (rr<32)
    int row = t & 127;
    int h = __builtin_amdgcn_readfirstlane(t >> 7);   // wave-uniform j-half -> s_load path
    const float* wsf = ws + O_WSF;
    const float* inrow = in + (size_t)rowbase * DD + dbase + c * 4;
    float4 pf[4];                                     // register prefetch buffer
    #pragma unroll
    for (int s = 0; s < 4; ++s)                       // preload stage 0
        pf[s] = *(const float4*)&inrow[(size_t)(s * 32 + rr) * DD];
    for (int stage = 0; stage < 4; ++stage) {
        int ds0 = stage * 32;                         // local d-offset
        float4 iv4 = *(const float4*)&inv_s[ds0 + c * 4];
        float4 mi4 = *(const float4*)&muinv_s[ds0 + c * 4];
        #pragma unroll
        for (int s = 0; s < 4; ++s) {                 // regs -> LDS, normalized
            int base = (s * 32 + rr) * 33 + c * 4;
            tile[base + 0] = pf[s].x * iv4.x - mi4.x;
            tile[base + 1] = pf[s].y * iv4.y - mi4.y;
            tile[base + 2] = pf[s].z * iv4.z - mi4.z;
            tile[base + 3] = pf[s].w * iv4.w - mi4.w;
        }
        __syncthreads();
        if (stage < 3) {                              // issue next stage's loads
            #pragma unroll
            for (int s = 0; s < 4; ++s)
                pf[s] = *(const float4*)&inrow[(size_t)(s * 32 + rr) * DD + (stage + 1) * 32];
        }
        const float* trow = tile + row * 33;          // compute current stage
        #pragma unroll 4
        for (int dl = 0; dl < 32; ++dl) {
            float xs = trow[dl];
            const float* wr = wsf + (size_t)(dbase + ds0 + dl) * 32 + h * 16;  // uniform -> s_load
            #pragma unroll
            for (int j = 0; j < 16; ++j) acc[j] += xs * wr[j];
        }
        __syncthreads();
    }
    float* dst = ypart + ((size_t)dg * BB + rowbase + row) * 32 + h * 16;
    #pragma unroll
    for (int j = 0; j < 16; j += 4)
        *(float4*)(dst + j) = make_float4(acc[j], acc[j+1], acc[j+2], acc[j+3]);
}

// ============ kC: reduce ypart -> yz; gram atomics (8-way split) ============
__global__ __launch_bounds__(256, 2)
void kC(float* __restrict__ ws) {
    __shared__ float yz_s[8 * 34];
    int b = blockIdx.x, t = threadIdx.x;
    int rowbase = b * 8;                              // 512 blocks x 8 rows
    int r = t >> 5, c = t & 31;
    const float* yp = ws + O_YPART;
    size_t off = (size_t)(rowbase + r) * 32 + c;
    float s = 0.f;
    #pragma unroll
    for (int dg = 0; dg < 32; ++dg) s += yp[(size_t)dg * (BB * 32) + off];
    ws[O_YZ + off] = s;
    yz_s[r * 34 + c] = s;
    if (c == 0) yz_s[r * 34 + 32] = 1.0f;
    __syncthreads();
    float* gm = ws + O_GRAMM + (size_t)(b & 7) * 1120;
    for (int p = t; p < 561; p += 256) {              // upper-tri pairs i<=j<=32
        int i = 0, rem = p;
        while (rem >= 33 - i) { rem -= 33 - i; ++i; }
        int j = i + rem;
        float a2 = 0.f;
        #pragma unroll
        for (int r2 = 0; r2 < 8; ++r2) a2 += yz_s[r2 * 34 + i] * yz_s[r2 * 34 + j];
        atomicAdd(&gm[i * 33 + j], a2);
    }
}

// ============ kE: barriered 17-dim solve (redundant/block) + epilogue =======
// Basis p=0..15 -> Y[:,p], p=16 -> ones. Gram cols: Y->p, Z_t->16+t, 1->32.
__global__ __launch_bounds__(256, 2)
void kE(const float* __restrict__ ws, float* __restrict__ out) {
    __shared__ __align__(16) float yzs[64 * 36];      // 64 rows of [Y|Z]
    __shared__ float GA[17 * 17], gz[17 * 16], v[15][17], gad[15][16],
                     gzd[15][16], gu[17], u[17], st[2], wm[17 * 16];
    int b = blockIdx.x, t = threadIdx.x;
    int rowbase = b * 64;                             // 64 blocks x 64 rows
    // stage this block's 64 rows of [Y|Z] (512 float4, 2/thread)
    const float4* src = (const float4*)(ws + O_YZ) + (size_t)rowbase * 8;
    #pragma unroll
    for (int k = 0; k < 2; ++k) {
        int idx = k * 256 + t;
        float4 f = src[idx];
        int row = idx >> 3, c4 = (idx & 7) * 4;
        yzs[row * 36 + c4 + 0] = f.x; yzs[row * 36 + c4 + 1] = f.y;
        yzs[row * 36 + c4 + 2] = f.z; yzs[row * 36 + c4 + 3] = f.w;
    }
    // gram (sum of 8 copies) -> LDS, all threads
    const float* gm = ws + O_GRAMM;
    for (int idx = t; idx < 17 * 17; idx += 256) {
        int p = idx / 17, q = idx % 17;
        int gi = gidx(p < 16 ? p : 32, q < 16 ? q : 32);
        float s = 0.f;
        #pragma unroll
        for (int m = 0; m < 8; ++m) s += gm[m * 1120 + gi];
        GA[idx] = s;
    }
    for (int idx = t; idx < 17 * 16; idx += 256) {
        int p = idx / 16, tt = idx % 16;
        int gi = gidx(p < 16 ? p : 32, 16 + tt);
        float s = 0.f;
        #pragma unroll
        for (int m = 0; m < 8; ++m) s += gm[m * 1120 + gi];
        gz[idx] = s;
    }
    if (t < 17) u[t] = (t == 0) ? 1.f : 0.f;
    __syncthreads();
    const float invB = 1.0f / BB;
    for (int i = 0; i < 15; ++i) {
        if (t < 17) {                                 // gu = GA @ u
            float s = 0.f;
            for (int q = 0; q < 17; ++q) s += GA[t * 17 + q] * u[q];
            gu[t] = s;
        }
        __syncthreads();
        if (t == 0) {                                 // stats of c_i
            float mean = gu[16] * invB, e2 = 0.f;
            for (int p = 0; p < 17; ++p) e2 += u[p] * gu[p];
            e2 *= invB;
            float var = e2 - mean * mean; if (var < 0.f) var = 0.f;
            st[0] = mean; st[1] = 1.0f / (sqrtf(var) + EPSF);
        }
        __syncthreads();
        if (t < 17) v[i][t] = (u[t] - (t == 16 ? st[0] : 0.f)) * st[1];
        __syncthreads();
        if (t < 16) {                                 // conv_i . Y[:,k]
            float s = 0.f;
            for (int p = 0; p < 17; ++p) s += v[i][p] * GA[p * 17 + t];
            gad[i][t] = s;
        } else if (t < 32) {                          // conv_i . Z[:,tt]
            int tt = t - 16;
            float s = 0.f;
            for (int p = 0; p < 17; ++p) s += v[i][p] * gz[p * 16 + tt];
            gzd[i][tt] = s;
        }
        __syncthreads();
        if (t < 17) {                                 // u_{i+1}
            float a2 = 0.f;
            for (int j = 0; j <= i; ++j) a2 += v[j][t] * gad[j][i + 1];
            u[t] = ((t == i + 1) ? 1.f : 0.f) - a2 * invB;
        }
        __syncthreads();
    }
    for (int idx = t; idx < 17 * 16; idx += 256) {
        int p = idx / 16, tt = idx % 16;
        float s = 0.f;
        for (int j = 0; j < tt; ++j) s += v[j][p] * gzd[j][tt];
        wm[idx] = s * invB;
    }
    __syncthreads();
    // epilogue: 4 outputs/thread, coalesced float4 store
    int row = t >> 2, c0 = (t & 3) * 4;
    const float* yr = yzs + row * 36;
    float o[4];
    #pragma unroll
    for (int k = 0; k < 4; ++k) o[k] = yr[16 + c0 + k] - wm[16 * 16 + c0 + k];
    #pragma unroll
    for (int p = 0; p < 16; ++p) {
        float yp = yr[p];
        #pragma unroll
        for (int k = 0; k < 4; ++k) o[k] -= yp * wm[p * 16 + c0 + k];
    }
    *(float4*)&out[(size_t)rowbase * 16 + t * 4] = make_float4(o[0], o[1], o[2], o[3]);
}

extern "C" void kernel_launch(void* const* d_in, const int* in_sizes, int n_in,
                              void* d_out, int out_size, void* d_ws, size_t ws_size,
                              hipStream_t stream) {
    const float* in    = (const float*)d_in[0];
    const float* W     = (const float*)d_in[1];
    const float* Wstat = (const float*)d_in[2];
    float* ws  = (float*)d_ws;
    float* out = (float*)d_out;

    kA<<<dim3(512),  dim3(256), 0, stream>>>(in, W, Wstat, ws);
    kB<<<dim3(1024), dim3(256), 0, stream>>>(in, ws, ws + O_YPART);
    kC<<<dim3(512),  dim3(256), 0, stream>>>(ws);
    kE<<<dim3(64),   dim3(256), 0, stream>>>(ws, out);
}

// Round 9
// 155.659 us; speedup vs baseline: 1.3009x; 1.0047x over previous
//
#include <hip/hip_runtime.h>
#include <stdint.h>

// FactorLayer: B=4096, D=4096, T=16, float32.
// X = znorm(inputs); Y = X@W_static; Z = X@W. All deflations use ORIGINAL X,
// so conv_j is fixed once born; everything lives in span{Y0..Y15, 1}.
// Sequential scan collapses to 17-dim recurrences on the Gram of [Y|Z|1];
// Out = Z - [Y|1] @ Wmat (17x16).  4 plain launches.
// Journal: R3 cooperative launch silently no-ops. R5 166us: kB 41us at 2
//   blocks/CU (grid-limited). R7 202us: j-half from raw t>>7 killed the
//   s_load weight path (SGPR 112->32, VMEM chain, kB 79us). R8 156us:
//   readfirstlane restored s_load, 4 blocks/CU, kB ~31us (tot-124 model).
// R9: kB -> 8 blocks/CU (2048 blocks = 32dg x 64 rowgroups of 64 rows),
//   8 j per thread via jq=readfirstlane(t>>6) (same proven pattern). 32
//   waves/CU. Tile 64x33 (bank-conflict-free stride kept). Rest unchanged.

#define BB 4096
#define DD 4096
#define EPSF 1e-6f

// ws layout (float indices), ~22 MB total
#define O_PART    0u          // [128 rowgroups][8192]: colsum(0..4095), colsq(4096..8191)
#define O_WSF     1048576u    // [d][32]: j<16 -> W_static (Y), j>=16 -> W (Z)
#define O_GRAMM   1179648u    // 8 copies x 1120 (33x33, upper-tri used)
#define O_YZ      1188608u    // [4096][32]  (byte offset 16B-aligned)
#define O_YPART   1319680u    // [32 dgroups][4096][32]

__device__ __forceinline__ int gidx(int a, int b) {   // upper-tri gram index
    int lo = a < b ? a : b, hi = a < b ? b : a;
    return lo * 33 + hi;
}

// ============ kA: stats partials + zero gram + stage weights ================
__global__ __launch_bounds__(256, 2)
void kA(const float* __restrict__ in, const float* __restrict__ W,
        const float* __restrict__ Wstat, float* __restrict__ ws) {
    int b = blockIdx.x, t = threadIdx.x;
    int idx = b * 256 + t;
    if (idx < 8960) ws[O_GRAMM + idx] = 0.f;          // 8 gram copies
    {                                                  // weights: 1 elt/thread
        int d = idx >> 5, j = idx & 31;
        ws[O_WSF + idx] = (j < 16) ? Wstat[d * 16 + j] : W[d * 16 + (j - 16)];
    }
    // stats: 4 colgroups x 128 rowgroups(32 rows); thread owns 4 cols
    int cgk = b & 3, rg = b >> 2;
    int c0 = cgk * 1024 + t * 4, r0 = rg * 32;
    float s0=0.f,s1=0.f,s2=0.f,s3=0.f,q0=0.f,q1=0.f,q2=0.f,q3=0.f;
    #pragma unroll 4
    for (int r = 0; r < 32; ++r) {
        float4 u = *(const float4*)&in[(size_t)(r0 + r) * DD + c0];
        s0 += u.x; q0 += u.x*u.x;  s1 += u.y; q1 += u.y*u.y;
        s2 += u.z; q2 += u.z*u.z;  s3 += u.w; q3 += u.w*u.w;
    }
    float* part = ws + O_PART + (size_t)rg * 8192;
    *(float4*)&part[c0]        = make_float4(s0, s1, s2, s3);
    *(float4*)&part[4096 + c0] = make_float4(q0, q1, q2, q3);
}

// ============ kB: finalize mu/inv; pipelined normalized GEMM ================
// 2048 blocks = 32 dgroups(128 d) x 64 rowgroups(64 rows). 8 blocks/CU.
// Thread role: row = t&63, jq = readfirstlane(t>>6) -> j in [jq*8, jq*8+8).
__global__ __launch_bounds__(256, 8)
void kB(const float* __restrict__ in, const float* __restrict__ ws,
        float* __restrict__ ypart) {
    __shared__ __align__(16) float tile[64 * 33];     // 8.4 KB
    __shared__ __align__(16) float mu_s[128];
    __shared__ __align__(16) float inv_s[128];
    __shared__ __align__(16) float muinv_s[128];
    int b = blockIdx.x, t = threadIdx.x;
    int dg = b & 31, rg = b >> 5;
    int dbase = dg * 128, rowbase = rg * 64;
    {   // prologue: reduce partials for this block's 128 cols (L2/L3-hot)
        int half = t >> 7, ci = t & 127;
        const float* p0 = ws + O_PART + (size_t)half * 4096 + dbase + ci;
        float a = 0.f;
        #pragma unroll 8
        for (int g = 0; g < 128; ++g) a += p0[(size_t)g * 8192];
        if (half == 0) mu_s[ci] = a * (1.0f / BB);
        __syncthreads();
        if (half == 1) {
            float m = mu_s[ci];
            float var = a * (1.0f / BB) - m * m; if (var < 0.f) var = 0.f;
            float iv = 1.0f / (sqrtf(var) + EPSF);
            inv_s[ci] = iv; muinv_s[ci] = m * iv;
        }
        __syncthreads();
    }
    float acc[8];
    #pragma unroll
    for (int i = 0; i < 8; ++i) acc[i] = 0.f;
    // staging role: thread covers (srow, chunk) and (srow+32, chunk)
    int chunk = t & 7, srow = t >> 3;                 // srow < 32
    int row = t & 63;
    int jq = __builtin_amdgcn_readfirstlane(t >> 6);  // wave-uniform -> s_load path
    const float* wsf = ws + O_WSF;
    const float* inp = in + (size_t)(rowbase + srow) * DD + dbase + chunk * 4;
    float4 pf0, pf1;                                  // register prefetch
    pf0 = *(const float4*)(inp);
    pf1 = *(const float4*)(inp + (size_t)32 * DD);
    for (int stage = 0; stage < 4; ++stage) {
        int ds0 = stage * 32;                         // local d-offset
        float4 iv4 = *(const float4*)&inv_s[ds0 + chunk * 4];
        float4 mi4 = *(const float4*)&muinv_s[ds0 + chunk * 4];
        int b0 = srow * 33 + chunk * 4;
        tile[b0 + 0] = pf0.x * iv4.x - mi4.x;         // regs -> LDS, normalized
        tile[b0 + 1] = pf0.y * iv4.y - mi4.y;
        tile[b0 + 2] = pf0.z * iv4.z - mi4.z;
        tile[b0 + 3] = pf0.w * iv4.w - mi4.w;
        int b1 = (srow + 32) * 33 + chunk * 4;
        tile[b1 + 0] = pf1.x * iv4.x - mi4.x;
        tile[b1 + 1] = pf1.y * iv4.y - mi4.y;
        tile[b1 + 2] = pf1.z * iv4.z - mi4.z;
        tile[b1 + 3] = pf1.w * iv4.w - mi4.w;
        __syncthreads();
        if (stage < 3) {                              // issue next stage's loads
            pf0 = *(const float4*)(inp + (stage + 1) * 32);
            pf1 = *(const float4*)(inp + (size_t)32 * DD + (stage + 1) * 32);
        }
        const float* trow = tile + row * 33;          // compute current stage
        #pragma unroll 4
        for (int dl = 0; dl < 32; ++dl) {
            float xs = trow[dl];
            const float* wr = wsf + (size_t)(dbase + ds0 + dl) * 32 + jq * 8;  // uniform -> s_load
            #pragma unroll
            for (int j = 0; j < 8; ++j) acc[j] += xs * wr[j];
        }
        __syncthreads();
    }
    float* dst = ypart + ((size_t)dg * BB + rowbase + row) * 32 + jq * 8;
    *(float4*)(dst + 0) = make_float4(acc[0], acc[1], acc[2], acc[3]);
    *(float4*)(dst + 4) = make_float4(acc[4], acc[5], acc[6], acc[7]);
}

// ============ kC: reduce ypart -> yz; gram atomics (8-way split) ============
__global__ __launch_bounds__(256, 2)
void kC(float* __restrict__ ws) {
    __shared__ float yz_s[8 * 34];
    int b = blockIdx.x, t = threadIdx.x;
    int rowbase = b * 8;                              // 512 blocks x 8 rows
    int r = t >> 5, c = t & 31;
    const float* yp = ws + O_YPART;
    size_t off = (size_t)(rowbase + r) * 32 + c;
    float s = 0.f;
    #pragma unroll
    for (int dg = 0; dg < 32; ++dg) s += yp[(size_t)dg * (BB * 32) + off];
    ws[O_YZ + off] = s;
    yz_s[r * 34 + c] = s;
    if (c == 0) yz_s[r * 34 + 32] = 1.0f;
    __syncthreads();
    float* gm = ws + O_GRAMM + (size_t)(b & 7) * 1120;
    for (int p = t; p < 561; p += 256) {              // upper-tri pairs i<=j<=32
        int i = 0, rem = p;
        while (rem >= 33 - i) { rem -= 33 - i; ++i; }
        int j = i + rem;
        float a2 = 0.f;
        #pragma unroll
        for (int r2 = 0; r2 < 8; ++r2) a2 += yz_s[r2 * 34 + i] * yz_s[r2 * 34 + j];
        atomicAdd(&gm[i * 33 + j], a2);
    }
}

// ============ kE: barriered 17-dim solve (redundant/block) + epilogue =======
// Basis p=0..15 -> Y[:,p], p=16 -> ones. Gram cols: Y->p, Z_t->16+t, 1->32.
__global__ __launch_bounds__(256, 2)
void kE(const float* __restrict__ ws, float* __restrict__ out) {
    __shared__ __align__(16) float yzs[64 * 36];      // 64 rows of [Y|Z]
    __shared__ float GA[17 * 17], gz[17 * 16], v[15][17], gad[15][16],
                     gzd[15][16], gu[17], u[17], st[2], wm[17 * 16];
    int b = blockIdx.x, t = threadIdx.x;
    int rowbase = b * 64;                             // 64 blocks x 64 rows
    // stage this block's 64 rows of [Y|Z] (512 float4, 2/thread)
    const float4* src = (const float4*)(ws + O_YZ) + (size_t)rowbase * 8;
    #pragma unroll
    for (int k = 0; k < 2; ++k) {
        int idx = k * 256 + t;
        float4 f = src[idx];
        int row = idx >> 3, c4 = (idx & 7) * 4;
        yzs[row * 36 + c4 + 0] = f.x; yzs[row * 36 + c4 + 1] = f.y;
        yzs[row * 36 + c4 + 2] = f.z; yzs[row * 36 + c4 + 3] = f.w;
    }
    // gram (sum of 8 copies) -> LDS, all threads
    const float* gm = ws + O_GRAMM;
    for (int idx = t; idx < 17 * 17; idx += 256) {
        int p = idx / 17, q = idx % 17;
        int gi = gidx(p < 16 ? p : 32, q < 16 ? q : 32);
        float s = 0.f;
        #pragma unroll
        for (int m = 0; m < 8; ++m) s += gm[m * 1120 + gi];
        GA[idx] = s;
    }
    for (int idx = t; idx < 17 * 16; idx += 256) {
        int p = idx / 16, tt = idx % 16;
        int gi = gidx(p < 16 ? p : 32, 16 + tt);
        float s = 0.f;
        #pragma unroll
        for (int m = 0; m < 8; ++m) s += gm[m * 1120 + gi];
        gz[idx] = s;
    }
    if (t < 17) u[t] = (t == 0) ? 1.f : 0.f;
    __syncthreads();
    const float invB = 1.0f / BB;
    for (int i = 0; i < 15; ++i) {
        if (t < 17) {                                 // gu = GA @ u
            float s = 0.f;
            for (int q = 0; q < 17; ++q) s += GA[t * 17 + q] * u[q];
            gu[t] = s;
        }
        __syncthreads();
        if (t == 0) {                                 // stats of c_i
            float mean = gu[16] * invB, e2 = 0.f;
            for (int p = 0; p < 17; ++p) e2 += u[p] * gu[p];
            e2 *= invB;
            float var = e2 - mean * mean; if (var < 0.f) var = 0.f;
            st[0] = mean; st[1] = 1.0f / (sqrtf(var) + EPSF);
        }
        __syncthreads();
        if (t < 17) v[i][t] = (u[t] - (t == 16 ? st[0] : 0.f)) * st[1];
        __syncthreads();
        if (t < 16) {                                 // conv_i . Y[:,k]
            float s = 0.f;
            for (int p = 0; p < 17; ++p) s += v[i][p] * GA[p * 17 + t];
            gad[i][t] = s;
        } else if (t < 32) {                          // conv_i . Z[:,tt]
            int tt = t - 16;
            float s = 0.f;
            for (int p = 0; p < 17; ++p) s += v[i][p] * gz[p * 16 + tt];
            gzd[i][tt] = s;
        }
        __syncthreads();
        if (t < 17) {                                 // u_{i+1}
            float a2 = 0.f;
            for (int j = 0; j <= i; ++j) a2 += v[j][t] * gad[j][i + 1];
            u[t] = ((t == i + 1) ? 1.f : 0.f) - a2 * invB;
        }
        __syncthreads();
    }
    for (int idx = t; idx < 17 * 16; idx += 256) {
        int p = idx / 16, tt = idx % 16;
        float s = 0.f;
        for (int j = 0; j < tt; ++j) s += v[j][p] * gzd[j][tt];
        wm[idx] = s * invB;
    }
    __syncthreads();
    // epilogue: 4 outputs/thread, coalesced float4 store
    int row = t >> 2, c0 = (t & 3) * 4;
    const float* yr = yzs + row * 36;
    float o[4];
    #pragma unroll
    for (int k = 0; k < 4; ++k) o[k] = yr[16 + c0 + k] - wm[16 * 16 + c0 + k];
    #pragma unroll
    for (int p = 0; p < 16; ++p) {
        float yp = yr[p];
        #pragma unroll
        for (int k = 0; k < 4; ++k) o[k] -= yp * wm[p * 16 + c0 + k];
    }
    *(float4*)&out[(size_t)rowbase * 16 + t * 4] = make_float4(o[0], o[1], o[2], o[3]);
}

extern "C" void kernel_launch(void* const* d_in, const int* in_sizes, int n_in,
                              void* d_out, int out_size, void* d_ws, size_t ws_size,
                              hipStream_t stream) {
    const float* in    = (const float*)d_in[0];
    const float* W     = (const float*)d_in[1];
    const float* Wstat = (const float*)d_in[2];
    float* ws  = (float*)d_ws;
    float* out = (float*)d_out;

    kA<<<dim3(512),  dim3(256), 0, stream>>>(in, W, Wstat, ws);
    kB<<<dim3(2048), dim3(256), 0, stream>>>(in, ws, ws + O_YPART);
    kC<<<dim3(512),  dim3(256), 0, stream>>>(ws);
    kE<<<dim3(64),   dim3(256), 0, stream>>>(ws, out);
}

// Round 10
// 151.602 us; speedup vs baseline: 1.3357x; 1.0268x over previous
//
#include <hip/hip_runtime.h>
#include <stdint.h>

// FactorLayer: B=4096, D=4096, T=16, float32.
// X = znorm(inputs); Y = X@W_static; Z = X@W; sequential deflation collapses
// to 17-dim recurrences on the Gram of [Y|Z|1]; Out = Z - [Y|1]@Wmat.
// R10 structure: fold diag(inv) into weights (Ws' = inv.*[Wstat|W], kernel kD)
// so kB is a PURE GEMM R = in @ Ws' (no per-block stats prologue -- R9's
// hidden 268 MB L2 tax). Shifts are recovered in kE via the centering
// identity: c_j = S_j/B with S_j = <R_j,1> = raw-Gram col 32, and
// <P_i,P_j> = Graw[i][j] - S_i S_j / B, <P_i,1> = 0.
// Journal: R3 coop launch no-ops. R7: weight ptr off raw t>>7 kills s_load
// (use readfirstlane). R5->R9: kB 41->31us; fixed harness cost ~124us.

#define BB 4096
#define DD 4096
#define EPSF 1e-6f

// ws layout (float indices)
#define O_PART    0u          // [128 rowgroups][8192]: colsum(0..4095), colsq(4096..8191)
#define O_WSF     1048576u    // Ws' [d][32]: j<16 -> inv*W_static, j>=16 -> inv*W
#define O_GRAMM   1179648u    // 8 copies x 1120 (33x33, upper-tri used)
#define O_YZ      1188608u    // [4096][32] raw R
#define O_YPART   1319680u    // [32 dgroups][4096][32]

__device__ __forceinline__ int gidx(int a, int b) {   // upper-tri gram index
    int lo = a < b ? a : b, hi = a < b ? b : a;
    return lo * 33 + hi;
}

// ============ kA: stats partials + zero gram copies =========================
__global__ __launch_bounds__(256, 2)
void kA(const float* __restrict__ in, float* __restrict__ ws) {
    int b = blockIdx.x, t = threadIdx.x;
    int idx = b * 256 + t;
    if (idx < 8960) ws[O_GRAMM + idx] = 0.f;          // 8 gram copies
    // stats: 4 colgroups x 128 rowgroups(32 rows); thread owns 4 cols
    int cgk = b & 3, rg = b >> 2;
    int c0 = cgk * 1024 + t * 4, r0 = rg * 32;
    float s0=0.f,s1=0.f,s2=0.f,s3=0.f,q0=0.f,q1=0.f,q2=0.f,q3=0.f;
    #pragma unroll 4
    for (int r = 0; r < 32; ++r) {
        float4 u = *(const float4*)&in[(size_t)(r0 + r) * DD + c0];
        s0 += u.x; q0 += u.x*u.x;  s1 += u.y; q1 += u.y*u.y;
        s2 += u.z; q2 += u.z*u.z;  s3 += u.w; q3 += u.w*u.w;
    }
    float* part = ws + O_PART + (size_t)rg * 8192;
    *(float4*)&part[c0]        = make_float4(s0, s1, s2, s3);
    *(float4*)&part[4096 + c0] = make_float4(q0, q1, q2, q3);
}

// ============ kD: partials -> inv_d; Ws' = inv.*[Wstat|W] ===================
// 128 blocks x 256 threads; block owns 32 columns.
__global__ __launch_bounds__(256, 4)
void kD(const float* __restrict__ W, const float* __restrict__ Wstat,
        float* __restrict__ ws) {
    __shared__ float red[32][9], redq[32][9], invs[32];
    int b = blockIdx.x, t = threadIdx.x;
    int dbase = b * 32;
    {   // phase 1: reduce 128 rowgroup partials (8 threads per column)
        int c1 = t & 31, k1 = t >> 5;
        const float* part = ws + O_PART;
        float s = 0.f, q = 0.f;
        #pragma unroll
        for (int i = 0; i < 16; ++i) {
            int g = k1 * 16 + i;
            s += part[(size_t)g * 8192 + dbase + c1];
            q += part[(size_t)g * 8192 + 4096 + dbase + c1];
        }
        red[c1][k1] = s; redq[c1][k1] = q;
    }
    __syncthreads();
    if (t < 32) {
        float ss = 0.f, qq = 0.f;
        #pragma unroll
        for (int i = 0; i < 8; ++i) { ss += red[t][i]; qq += redq[t][i]; }
        float m = ss * (1.0f / BB);
        float var = qq * (1.0f / BB) - m * m; if (var < 0.f) var = 0.f;
        invs[t] = 1.0f / (sqrtf(var) + EPSF);
    }
    __syncthreads();
    {   // phase 2: scale & stage weights (lanes vary j fastest -> coalesced)
        int c2 = t >> 3, j0 = (t & 7) * 4;
        int d = dbase + c2;
        float iv = invs[c2];
        float4 wv = (j0 < 16) ? *(const float4*)&Wstat[d * 16 + j0]
                              : *(const float4*)&W[d * 16 + (j0 - 16)];
        *(float4*)&ws[O_WSF + (size_t)d * 32 + j0] =
            make_float4(wv.x * iv, wv.y * iv, wv.z * iv, wv.w * iv);
    }
}

// ============ kB: pure GEMM R = in @ Ws' -> ypart ===========================
// 2048 blocks = 32 dgroups(128 d) x 64 rowgroups(64 rows). 8 blocks/CU.
// Thread: row = t&63, jq = readfirstlane(t>>6) -> j in [jq*8, jq*8+8).
__global__ __launch_bounds__(256, 8)
void kB(const float* __restrict__ in, const float* __restrict__ ws,
        float* __restrict__ ypart) {
    __shared__ __align__(16) float tile[64 * 33];     // 8.4 KB
    int b = blockIdx.x, t = threadIdx.x;
    int dg = b & 31, rg = b >> 5;
    int dbase = dg * 128, rowbase = rg * 64;
    float acc[8];
    #pragma unroll
    for (int i = 0; i < 8; ++i) acc[i] = 0.f;
    int chunk = t & 7, srow = t >> 3;                 // staging role (srow<32)
    int row = t & 63;
    int jq = __builtin_amdgcn_readfirstlane(t >> 6);  // wave-uniform -> s_load
    const float* wsf = ws + O_WSF;
    const float* inp = in + (size_t)(rowbase + srow) * DD + dbase + chunk * 4;
    float4 pf0 = *(const float4*)(inp);
    float4 pf1 = *(const float4*)(inp + (size_t)32 * DD);
    for (int stage = 0; stage < 4; ++stage) {
        int ds0 = stage * 32;
        int b0 = srow * 33 + chunk * 4;
        tile[b0 + 0] = pf0.x; tile[b0 + 1] = pf0.y;
        tile[b0 + 2] = pf0.z; tile[b0 + 3] = pf0.w;
        int b1 = (srow + 32) * 33 + chunk * 4;
        tile[b1 + 0] = pf1.x; tile[b1 + 1] = pf1.y;
        tile[b1 + 2] = pf1.z; tile[b1 + 3] = pf1.w;
        __syncthreads();
        if (stage < 3) {                              // prefetch next stage
            pf0 = *(const float4*)(inp + (stage + 1) * 32);
            pf1 = *(const float4*)(inp + (size_t)32 * DD + (stage + 1) * 32);
        }
        const float* trow = tile + row * 33;
        #pragma unroll 4
        for (int dl = 0; dl < 32; ++dl) {
            float xs = trow[dl];
            const float* wr = wsf + (size_t)(dbase + ds0 + dl) * 32 + jq * 8;
            #pragma unroll
            for (int j = 0; j < 8; ++j) acc[j] += xs * wr[j];
        }
        __syncthreads();
    }
    float* dst = ypart + ((size_t)dg * BB + rowbase + row) * 32 + jq * 8;
    *(float4*)(dst + 0) = make_float4(acc[0], acc[1], acc[2], acc[3]);
    *(float4*)(dst + 4) = make_float4(acc[4], acc[5], acc[6], acc[7]);
}

// ============ kC: reduce ypart -> yz (raw R); gram atomics (8-way) ==========
__global__ __launch_bounds__(256, 2)
void kC(float* __restrict__ ws) {
    __shared__ float yz_s[8 * 34];
    int b = blockIdx.x, t = threadIdx.x;
    int rowbase = b * 8;                              // 512 blocks x 8 rows
    int r = t >> 5, c = t & 31;
    const float* yp = ws + O_YPART;
    size_t off = (size_t)(rowbase + r) * 32 + c;
    float s = 0.f;
    #pragma unroll
    for (int dg = 0; dg < 32; ++dg) s += yp[(size_t)dg * (BB * 32) + off];
    ws[O_YZ + off] = s;
    yz_s[r * 34 + c] = s;
    if (c == 0) yz_s[r * 34 + 32] = 1.0f;
    __syncthreads();
    float* gm = ws + O_GRAMM + (size_t)(b & 7) * 1120;
    for (int p = t; p < 561; p += 256) {              // upper-tri pairs i<=j<=32
        int i = 0, rem = p;
        while (rem >= 33 - i) { rem -= 33 - i; ++i; }
        int j = i + rem;
        float a2 = 0.f;
        #pragma unroll
        for (int r2 = 0; r2 < 8; ++r2) a2 += yz_s[r2 * 34 + i] * yz_s[r2 * 34 + j];
        atomicAdd(&gm[i * 33 + j], a2);
    }
}

// ============ kE: centered-Gram 17-dim solve + epilogue =====================
// Basis p=0..15 -> Y[:,p], p=16 -> ones. True Gram from raw: G = Graw - SS^T/B;
// <P,1> = 0. Epilogue on raw R with ones-row of Wmat adjusted by the shifts.
__global__ __launch_bounds__(256, 2)
void kE(const float* __restrict__ ws, float* __restrict__ out) {
    __shared__ __align__(16) float yzs[64 * 36];      // 64 rows of raw [Ry|Rz]
    __shared__ float Sv[33], GA[17 * 17], gz[17 * 16], v[15][17], gad[15][16],
                     gzd[15][16], gu[17], u[17], st[2], wm[17 * 16];
    int b = blockIdx.x, t = threadIdx.x;
    int rowbase = b * 64;                             // 64 blocks x 64 rows
    const float invB = 1.0f / BB;
    // stage this block's 64 rows of raw R (512 float4, 2/thread)
    const float4* src = (const float4*)(ws + O_YZ) + (size_t)rowbase * 8;
    #pragma unroll
    for (int k = 0; k < 2; ++k) {
        int idx = k * 256 + t;
        float4 f = src[idx];
        int row = idx >> 3, c4 = (idx & 7) * 4;
        yzs[row * 36 + c4 + 0] = f.x; yzs[row * 36 + c4 + 1] = f.y;
        yzs[row * 36 + c4 + 2] = f.z; yzs[row * 36 + c4 + 3] = f.w;
    }
    const float* gm = ws + O_GRAMM;
    if (t < 33) {                                     // S_i = <R_i, 1> (i=32: B)
        float s = 0.f;
        #pragma unroll
        for (int m = 0; m < 8; ++m) s += gm[m * 1120 + gidx(t, 32)];
        Sv[t] = s;
    }
    __syncthreads();
    for (int idx = t; idx < 17 * 17; idx += 256) {    // centered GA
        int p = idx / 17, q = idx % 17;
        float val;
        if (p < 16 && q < 16) {
            float raw = 0.f;
            #pragma unroll
            for (int m = 0; m < 8; ++m) raw += gm[m * 1120 + gidx(p, q)];
            val = raw - Sv[p] * Sv[q] * invB;
        } else if (p == 16 && q == 16) val = (float)BB;
        else val = 0.f;                               // <P,1> = 0 exactly
        GA[idx] = val;
    }
    for (int idx = t; idx < 17 * 16; idx += 256) {    // centered gz
        int p = idx / 16, tt = idx % 16;
        float val = 0.f;
        if (p < 16) {
            float raw = 0.f;
            #pragma unroll
            for (int m = 0; m < 8; ++m) raw += gm[m * 1120 + gidx(p, 16 + tt)];
            val = raw - Sv[p] * Sv[16 + tt] * invB;
        }
        gz[idx] = val;
    }
    if (t < 17) u[t] = (t == 0) ? 1.f : 0.f;
    __syncthreads();
    for (int i = 0; i < 15; ++i) {
        if (t < 17) {                                 // gu = GA @ u
            float s = 0.f;
            for (int q = 0; q < 17; ++q) s += GA[t * 17 + q] * u[q];
            gu[t] = s;
        }
        __syncthreads();
        if (t == 0) {                                 // stats of c_i
            float mean = gu[16] * invB, e2 = 0.f;
            for (int p = 0; p < 17; ++p) e2 += u[p] * gu[p];
            e2 *= invB;
            float var = e2 - mean * mean; if (var < 0.f) var = 0.f;
            st[0] = mean; st[1] = 1.0f / (sqrtf(var) + EPSF);
        }
        __syncthreads();
        if (t < 17) v[i][t] = (u[t] - (t == 16 ? st[0] : 0.f)) * st[1];
        __syncthreads();
        if (t < 16) {                                 // conv_i . Y[:,k]
            float s = 0.f;
            for (int p = 0; p < 17; ++p) s += v[i][p] * GA[p * 17 + t];
            gad[i][t] = s;
        } else if (t < 32) {                          // conv_i . Z[:,tt]
            int tt = t - 16;
            float s = 0.f;
            for (int p = 0; p < 17; ++p) s += v[i][p] * gz[p * 16 + tt];
            gzd[i][tt] = s;
        }
        __syncthreads();
        if (t < 17) {                                 // u_{i+1}
            float a2 = 0.f;
            for (int j = 0; j <= i; ++j) a2 += v[j][t] * gad[j][i + 1];
            u[t] = ((t == i + 1) ? 1.f : 0.f) - a2 * invB;
        }
        __syncthreads();
    }
    for (int idx = t; idx < 17 * 16; idx += 256) {
        int p = idx / 16, tt = idx % 16;
        float s = 0.f;
        for (int j = 0; j < tt; ++j) s += v[j][p] * gzd[j][tt];
        wm[idx] = s * invB;
    }
    __syncthreads();
    if (t < 16) {                                     // fold shifts into ones-row:
        float adj = Sv[16 + t] * invB;                // wm2 = wm + cz - sum cy*wm
        for (int p = 0; p < 16; ++p) adj -= Sv[p] * invB * wm[p * 16 + t];
        wm[16 * 16 + t] += adj;
    }
    __syncthreads();
    // epilogue on raw R: 4 outputs/thread, coalesced float4 store
    int row = t >> 2, c0 = (t & 3) * 4;
    const float* yr = yzs + row * 36;
    float o[4];
    #pragma unroll
    for (int k = 0; k < 4; ++k) o[k] = yr[16 + c0 + k] - wm[16 * 16 + c0 + k];
    #pragma unroll
    for (int p = 0; p < 16; ++p) {
        float yp = yr[p];
        #pragma unroll
        for (int k = 0; k < 4; ++k) o[k] -= yp * wm[p * 16 + c0 + k];
    }
    *(float4*)&out[(size_t)rowbase * 16 + t * 4] = make_float4(o[0], o[1], o[2], o[3]);
}

extern "C" void kernel_launch(void* const* d_in, const int* in_sizes, int n_in,
                              void* d_out, int out_size, void* d_ws, size_t ws_size,
                              hipStream_t stream) {
    const float* in    = (const float*)d_in[0];
    const float* W     = (const float*)d_in[1];
    const float* Wstat = (const float*)d_in[2];
    float* ws  = (float*)d_ws;
    float* out = (float*)d_out;

    kA<<<dim3(512),  dim3(256), 0, stream>>>(in, ws);
    kD<<<dim3(128),  dim3(256), 0, stream>>>(W, Wstat, ws);
    kB<<<dim3(2048), dim3(256), 0, stream>>>(in, ws, ws + O_YPART);
    kC<<<dim3(512),  dim3(256), 0, stream>>>(ws);
    kE<<<dim3(64),   dim3(256), 0, stream>>>(ws, out);
}

// Round 11
// 149.150 us; speedup vs baseline: 1.3577x; 1.0164x over previous
//
#include <hip/hip_runtime.h>
#include <stdint.h>

// FactorLayer: B=4096, D=4096, T=16, float32.
// X = znorm(inputs); Y = X@W_static; Z = X@W; sequential deflation collapses
// to 17-dim recurrences on the Gram of [Y|Z|1]; Out = Z - [Y|1]@Wmat.
// Structure (R11): 4 launches. kA: stats partials ([16][8192], 512 KB,
// L2-resident) via intra-block LDS reduce + zero gram. kB: pure GEMM
// R = (in.diag(inv)) @ [Wstat|W] with a 16 KB inv-prologue per block (kills
// R10's kD + one ~7us launch gap; avoids R9's 131KB/block prologue tax);
// weights s_load'ed RAW via wave-uniform jq base select. kC: reduce + gram.
// kE: centered-Gram solve (shifts recovered via S_j = raw-Gram col 32).
// Journal: R3 coop launch no-ops. R7: weight ptr off raw t>>7 kills s_load
// (use readfirstlane). Launch gap ~6-7us (R2->R5 calibration). Fixed harness
// cost (fills+restore+gaps) ~110us; controllable kernel floor ~26us.

#define BB 4096
#define DD 4096
#define EPSF 1e-6f

// ws layout (float indices)
#define O_PART    0u          // [16 rowgroups][8192]: colsum(0..4095), colsq(4096..8191)
#define O_GRAMM   131072u     // 8 copies x 1120 (33x33, upper-tri used)
#define O_YZ      140288u     // [4096][32] raw R (16B-aligned)
#define O_YPART   271360u     // [32 dgroups][4096][32] (16B-aligned)

__device__ __forceinline__ int gidx(int a, int b) {   // upper-tri gram index
    int lo = a < b ? a : b, hi = a < b ? b : a;
    return lo * 33 + hi;
}

// ============ kA: stats partials (16 rowgroups) + zero gram =================
// 512 blocks = 32 colgroups(128 cols) x 16 rowgroups(256 rows).
__global__ __launch_bounds__(256, 2)
void kA(const float* __restrict__ in, float* __restrict__ ws) {
    __shared__ float rs[8 * 132], rq[8 * 132];        // pad 132: avoid 8-way bank hits
    int b = blockIdx.x, t = threadIdx.x;
    int idx = b * 256 + t;
    if (idx < 8960) ws[O_GRAMM + idx] = 0.f;          // 8 gram copies
    int cg = b & 31, rg = b >> 5;
    int dbase = cg * 128, r0 = rg * 256;
    int chunk = t & 31, rr = t >> 5;
    int c0 = dbase + chunk * 4;
    float s0=0.f,s1=0.f,s2=0.f,s3=0.f,q0=0.f,q1=0.f,q2=0.f,q3=0.f;
    #pragma unroll 4
    for (int i = 0; i < 32; ++i) {
        int r = r0 + i * 8 + rr;
        float4 u = *(const float4*)&in[(size_t)r * DD + c0];
        s0 += u.x; q0 += u.x*u.x;  s1 += u.y; q1 += u.y*u.y;
        s2 += u.z; q2 += u.z*u.z;  s3 += u.w; q3 += u.w*u.w;
    }
    int lb = rr * 132 + chunk * 4;
    rs[lb+0]=s0; rs[lb+1]=s1; rs[lb+2]=s2; rs[lb+3]=s3;
    rq[lb+0]=q0; rq[lb+1]=q1; rq[lb+2]=q2; rq[lb+3]=q3;
    __syncthreads();
    float* part = ws + O_PART + (size_t)rg * 8192;
    if (t < 128) {                                    // finalize sums
        float a = 0.f;
        #pragma unroll
        for (int r2 = 0; r2 < 8; ++r2) a += rs[r2 * 132 + t];
        part[dbase + t] = a;
    } else {                                          // finalize sumsqs
        int ci = t - 128;
        float a = 0.f;
        #pragma unroll
        for (int r2 = 0; r2 < 8; ++r2) a += rq[r2 * 132 + ci];
        part[4096 + dbase + ci] = a;
    }
}

// ============ kB: inv-prologue + pure GEMM R = (in.inv) @ Wcat ==============
// 2048 blocks = 32 dgroups(128 d) x 64 rowgroups(64 rows). 8 blocks/CU.
// Thread: row = t&63, jq = readfirstlane(t>>6) -> j in [jq*8, jq*8+8).
__global__ __launch_bounds__(256, 8)
void kB(const float* __restrict__ in, const float* __restrict__ W,
        const float* __restrict__ Wstat, float* __restrict__ ws,
        float* __restrict__ ypart) {
    __shared__ __align__(16) float tile[64 * 33];     // 8.4 KB
    __shared__ __align__(16) float inv_s[128];
    int b = blockIdx.x, t = threadIdx.x;
    int dg = b & 31, rg = b >> 5;
    int dbase = dg * 128, rowbase = rg * 64;
    int chunk = t & 7, srow = t >> 3;                 // staging role (srow<32)
    int row = t & 63;
    int jq = __builtin_amdgcn_readfirstlane(t >> 6);  // wave-uniform -> s_load
    const float* inp = in + (size_t)(rowbase + srow) * DD + dbase + chunk * 4;
    float4 pf0 = *(const float4*)(inp);               // prefetch overlaps prologue
    float4 pf1 = *(const float4*)(inp + (size_t)32 * DD);
    {   // prologue: inv for this block's 128 cols from 16 KB L2-hot partials
        if (t < 128) {
            const float* part = ws + O_PART;
            float s = 0.f, q = 0.f;
            #pragma unroll
            for (int g = 0; g < 16; ++g) {
                s += part[(size_t)g * 8192 + dbase + t];
                q += part[(size_t)g * 8192 + 4096 + dbase + t];
            }
            float m = s * (1.0f / BB);
            float var = q * (1.0f / BB) - m * m; if (var < 0.f) var = 0.f;
            inv_s[t] = 1.0f / (sqrtf(var) + EPSF);
        }
        __syncthreads();
    }
    float acc[8];
    #pragma unroll
    for (int i = 0; i < 8; ++i) acc[i] = 0.f;
    // raw weight base: wave-uniform jq -> scalar loads (R7 lesson)
    const float* wbase = (jq < 2) ? (Wstat + jq * 8) : (W + (jq - 2) * 8);
    for (int stage = 0; stage < 4; ++stage) {
        int ds0 = stage * 32;
        float4 iv4 = *(const float4*)&inv_s[ds0 + chunk * 4];
        int b0 = srow * 33 + chunk * 4;               // scale folded into staging
        tile[b0 + 0] = pf0.x * iv4.x; tile[b0 + 1] = pf0.y * iv4.y;
        tile[b0 + 2] = pf0.z * iv4.z; tile[b0 + 3] = pf0.w * iv4.w;
        int b1 = (srow + 32) * 33 + chunk * 4;
        tile[b1 + 0] = pf1.x * iv4.x; tile[b1 + 1] = pf1.y * iv4.y;
        tile[b1 + 2] = pf1.z * iv4.z; tile[b1 + 3] = pf1.w * iv4.w;
        __syncthreads();
        if (stage < 3) {                              // prefetch next stage
            pf0 = *(const float4*)(inp + (stage + 1) * 32);
            pf1 = *(const float4*)(inp + (size_t)32 * DD + (stage + 1) * 32);
        }
        const float* trow = tile + row * 33;
        #pragma unroll 4
        for (int dl = 0; dl < 32; ++dl) {
            float xs = trow[dl];
            const float* wr = wbase + (size_t)(dbase + ds0 + dl) * 16;
            #pragma unroll
            for (int j = 0; j < 8; ++j) acc[j] += xs * wr[j];
        }
        __syncthreads();
    }
    float* dst = ypart + ((size_t)dg * BB + rowbase + row) * 32 + jq * 8;
    *(float4*)(dst + 0) = make_float4(acc[0], acc[1], acc[2], acc[3]);
    *(float4*)(dst + 4) = make_float4(acc[4], acc[5], acc[6], acc[7]);
}

// ============ kC: reduce ypart -> yz (raw R); gram atomics (8-way) ==========
__global__ __launch_bounds__(256, 2)
void kC(float* __restrict__ ws) {
    __shared__ float yz_s[8 * 34];
    int b = blockIdx.x, t = threadIdx.x;
    int rowbase = b * 8;                              // 512 blocks x 8 rows
    int r = t >> 5, c = t & 31;
    const float* yp = ws + O_YPART;
    size_t off = (size_t)(rowbase + r) * 32 + c;
    float s = 0.f;
    #pragma unroll
    for (int dg = 0; dg < 32; ++dg) s += yp[(size_t)dg * (BB * 32) + off];
    ws[O_YZ + off] = s;
    yz_s[r * 34 + c] = s;
    if (c == 0) yz_s[r * 34 + 32] = 1.0f;
    __syncthreads();
    float* gm = ws + O_GRAMM + (size_t)(b & 7) * 1120;
    for (int p = t; p < 561; p += 256) {              // upper-tri pairs i<=j<=32
        int i = 0, rem = p;
        while (rem >= 33 - i) { rem -= 33 - i; ++i; }
        int j = i + rem;
        float a2 = 0.f;
        #pragma unroll
        for (int r2 = 0; r2 < 8; ++r2) a2 += yz_s[r2 * 34 + i] * yz_s[r2 * 34 + j];
        atomicAdd(&gm[i * 33 + j], a2);
    }
}

// ============ kE: centered-Gram 17-dim solve + epilogue =====================
// Basis p=0..15 -> Y[:,p], p=16 -> ones. True Gram from raw: G = Graw - SS^T/B;
// <P,1> = 0. Epilogue on raw R with ones-row of Wmat adjusted by the shifts.
__global__ __launch_bounds__(256, 2)
void kE(const float* __restrict__ ws, float* __restrict__ out) {
    __shared__ __align__(16) float yzs[64 * 36];      // 64 rows of raw [Ry|Rz]
    __shared__ float Sv[33], GA[17 * 17], gz[17 * 16], v[15][17], gad[15][16],
                     gzd[15][16], gu[17], u[17], st[2], wm[17 * 16];
    int b = blockIdx.x, t = threadIdx.x;
    int rowbase = b * 64;                             // 64 blocks x 64 rows
    const float invB = 1.0f / BB;
    const float4* src = (const float4*)(ws + O_YZ) + (size_t)rowbase * 8;
    #pragma unroll
    for (int k = 0; k < 2; ++k) {
        int idx = k * 256 + t;
        float4 f = src[idx];
        int row = idx >> 3, c4 = (idx & 7) * 4;
        yzs[row * 36 + c4 + 0] = f.x; yzs[row * 36 + c4 + 1] = f.y;
        yzs[row * 36 + c4 + 2] = f.z; yzs[row * 36 + c4 + 3] = f.w;
    }
    const float* gm = ws + O_GRAMM;
    if (t < 33) {                                     // S_i = <R_i, 1> (i=32: B)
        float s = 0.f;
        #pragma unroll
        for (int m = 0; m < 8; ++m) s += gm[m * 1120 + gidx(t, 32)];
        Sv[t] = s;
    }
    __syncthreads();
    for (int idx = t; idx < 17 * 17; idx += 256) {    // centered GA
        int p = idx / 17, q = idx % 17;
        float val;
        if (p < 16 && q < 16) {
            float raw = 0.f;
            #pragma unroll
            for (int m = 0; m < 8; ++m) raw += gm[m * 1120 + gidx(p, q)];
            val = raw - Sv[p] * Sv[q] * invB;
        } else if (p == 16 && q == 16) val = (float)BB;
        else val = 0.f;                               // <P,1> = 0 exactly
        GA[idx] = val;
    }
    for (int idx = t; idx < 17 * 16; idx += 256) {    // centered gz
        int p = idx / 16, tt = idx % 16;
        float val = 0.f;
        if (p < 16) {
            float raw = 0.f;
            #pragma unroll
            for (int m = 0; m < 8; ++m) raw += gm[m * 1120 + gidx(p, 16 + tt)];
            val = raw - Sv[p] * Sv[16 + tt] * invB;
        }
        gz[idx] = val;
    }
    if (t < 17) u[t] = (t == 0) ? 1.f : 0.f;
    __syncthreads();
    for (int i = 0; i < 15; ++i) {
        if (t < 17) {                                 // gu = GA @ u
            float s = 0.f;
            for (int q = 0; q < 17; ++q) s += GA[t * 17 + q] * u[q];
            gu[t] = s;
        }
        __syncthreads();
        if (t == 0) {                                 // stats of c_i
            float mean = gu[16] * invB, e2 = 0.f;
            for (int p = 0; p < 17; ++p) e2 += u[p] * gu[p];
            e2 *= invB;
            float var = e2 - mean * mean; if (var < 0.f) var = 0.f;
            st[0] = mean; st[1] = 1.0f / (sqrtf(var) + EPSF);
        }
        __syncthreads();
        if (t < 17) v[i][t] = (u[t] - (t == 16 ? st[0] : 0.f)) * st[1];
        __syncthreads();
        if (t < 16) {                                 // conv_i . Y[:,k]
            float s = 0.f;
            for (int p = 0; p < 17; ++p) s += v[i][p] * GA[p * 17 + t];
            gad[i][t] = s;
        } else if (t < 32) {                          // conv_i . Z[:,tt]
            int tt = t - 16;
            float s = 0.f;
            for (int p = 0; p < 17; ++p) s += v[i][p] * gz[p * 16 + tt];
            gzd[i][tt] = s;
        }
        __syncthreads();
        if (t < 17) {                                 // u_{i+1}
            float a2 = 0.f;
            for (int j = 0; j <= i; ++j) a2 += v[j][t] * gad[j][i + 1];
            u[t] = ((t == i + 1) ? 1.f : 0.f) - a2 * invB;
        }
        __syncthreads();
    }
    for (int idx = t; idx < 17 * 16; idx += 256) {
        int p = idx / 16, tt = idx % 16;
        float s = 0.f;
        for (int j = 0; j < tt; ++j) s += v[j][p] * gzd[j][tt];
        wm[idx] = s * invB;
    }
    __syncthreads();
    if (t < 16) {                                     // fold shifts into ones-row
        float adj = Sv[16 + t] * invB;
        for (int p = 0; p < 16; ++p) adj -= Sv[p] * invB * wm[p * 16 + t];
        wm[16 * 16 + t] += adj;
    }
    __syncthreads();
    int row = t >> 2, c0 = (t & 3) * 4;
    const float* yr = yzs + row * 36;
    float o[4];
    #pragma unroll
    for (int k = 0; k < 4; ++k) o[k] = yr[16 + c0 + k] - wm[16 * 16 + c0 + k];
    #pragma unroll
    for (int p = 0; p < 16; ++p) {
        float yp = yr[p];
        #pragma unroll
        for (int k = 0; k < 4; ++k) o[k] -= yp * wm[p * 16 + c0 + k];
    }
    *(float4*)&out[(size_t)rowbase * 16 + t * 4] = make_float4(o[0], o[1], o[2], o[3]);
}

extern "C" void kernel_launch(void* const* d_in, const int* in_sizes, int n_in,
                              void* d_out, int out_size, void* d_ws, size_t ws_size,
                              hipStream_t stream) {
    const float* in    = (const float*)d_in[0];
    const float* W     = (const float*)d_in[1];
    const float* Wstat = (const float*)d_in[2];
    float* ws  = (float*)d_ws;
    float* out = (float*)d_out;

    kA<<<dim3(512),  dim3(256), 0, stream>>>(in, ws);
    kB<<<dim3(2048), dim3(256), 0, stream>>>(in, W, Wstat, ws, ws + O_YPART);
    kC<<<dim3(512),  dim3(256), 0, stream>>>(ws);
    kE<<<dim3(64),   dim3(256), 0, stream>>>(ws, out);
}